// Round 3
// baseline (12805.917 us; speedup 1.0000x reference)
//
#include <hip/hip_runtime.h>

#define NP   16384
#define KNN  32
#define HDIM 128
#define ODIM 64

// ---------------- squared norms ----------------
template<int D>
__global__ __launch_bounds__(256)
void sq_kernel(const float* __restrict__ X, float* __restrict__ sq) {
    const int lane = threadIdx.x & 63;
    const int row  = blockIdx.x * 4 + (threadIdx.x >> 6);
    float s = 0.f;
    #pragma unroll
    for (int d = lane; d < D; d += 64) {
        const float v = X[(size_t)row * D + d];
        s = fmaf(v, v, s);
    }
    #pragma unroll
    for (int off = 32; off; off >>= 1) s += __shfl_down(s, off);
    if (lane == 0) sq[row] = s;
}

// ---------------- top-32 neighbors (streaming) ----------------
// score_j = dot(x_i, x_j) - 0.5*sq_j  (argmax score == argmin d2 per row)
template<int D>
__global__ __launch_bounds__(256)
void topk_kernel(const float* __restrict__ X, const float* __restrict__ sq,
                 int* __restrict__ topIdx) {
    constexpr int TI = 64, JC = 64;
    __shared__ float xiT[D][68];        // transposed i-row tile, padded
    __shared__ float xjT[D][68];        // transposed j-tile; aliased as scores[64][64]
    __shared__ float sqj[JC];
    __shared__ float topv[TI][KNN];
    __shared__ int   topi[TI][KNN];
    __shared__ float minv[TI];

    const int t = threadIdx.x;
    const int rowBase = blockIdx.x * TI;
    const int tj = t & 15, ti = t >> 4;
    const int lane = t & 63, wave = t >> 6;
    const int i4 = ti * 4, j4 = tj * 4;
    float* const scores = &xjT[0][0];   // 64*64 floats, fits in D*68 (D>=64)

    for (int e = t; e < TI * (D / 4); e += 256) {
        const float4 v = reinterpret_cast<const float4*>(X + (size_t)rowBase * D)[e];
        const int i = e / (D / 4);
        const int d = (e % (D / 4)) * 4;
        xiT[d + 0][i] = v.x; xiT[d + 1][i] = v.y;
        xiT[d + 2][i] = v.z; xiT[d + 3][i] = v.w;
    }
    for (int e = t; e < TI * KNN; e += 256) {
        topv[e >> 5][e & 31] = -__builtin_inff();
        topi[e >> 5][e & 31] = 0;
    }
    if (t < TI) minv[t] = -__builtin_inff();
    __syncthreads();

    for (int jb = 0; jb < NP; jb += JC) {
        for (int e = t; e < JC * (D / 4); e += 256) {
            const float4 v = reinterpret_cast<const float4*>(X + (size_t)jb * D)[e];
            const int j = e / (D / 4);
            const int d = (e % (D / 4)) * 4;
            xjT[d + 0][j] = v.x; xjT[d + 1][j] = v.y;
            xjT[d + 2][j] = v.z; xjT[d + 3][j] = v.w;
        }
        if (t < JC) sqj[t] = sq[jb + t];
        __syncthreads();

        float acc[4][4];
        #pragma unroll
        for (int a = 0; a < 4; ++a)
            #pragma unroll
            for (int b = 0; b < 4; ++b) acc[a][b] = 0.f;

        #pragma unroll 4
        for (int d = 0; d < D; ++d) {
            const float4 xv = *reinterpret_cast<const float4*>(&xiT[d][i4]);
            const float4 yv = *reinterpret_cast<const float4*>(&xjT[d][j4]);
            const float xa[4] = {xv.x, xv.y, xv.z, xv.w};
            const float xb[4] = {yv.x, yv.y, yv.z, yv.w};
            #pragma unroll
            for (int a = 0; a < 4; ++a)
                #pragma unroll
                for (int b = 0; b < 4; ++b)
                    acc[a][b] = fmaf(xa[a], xb[b], acc[a][b]);
        }
        __syncthreads();   // all waves done reading xjT as xj

        // wave w writes score rows [w*16, w*16+16) and is their only reader
        #pragma unroll
        for (int a = 0; a < 4; ++a)
            #pragma unroll
            for (int b = 0; b < 4; ++b)
                scores[(i4 + a) * 64 + (j4 + b)] = acc[a][b] - 0.5f * sqj[j4 + b];

        // per-wave streaming top-k update; wave owns rows [wave*16, wave*16+16)
        #pragma unroll 1
        for (int r = 0; r < 16; ++r) {
            const int lr = wave * 16 + r;
            const float sv = scores[lr * 64 + lane];
            const float mv = minv[lr];
            unsigned long long mask = __ballot(sv > mv);
            while (mask) {
                const int l = __builtin_ctzll(mask);   // ascending j => stable ties
                mask &= mask - 1;
                const float cv = __shfl(sv, l);
                const int   cj = jb + l;
                float v  = (lane < KNN) ? topv[lr][lane] : __builtin_inff();
                int   si = (lane < KNN) ? topi[lr][lane] : 0x7fffffff;
                int   pos = lane;
                #pragma unroll
                for (int off = 32; off; off >>= 1) {
                    const float ov = __shfl_down(v, off);
                    const int   oi = __shfl_down(si, off);
                    const int   op = __shfl_down(pos, off);
                    if (ov < v || (ov == v && oi > si)) { v = ov; si = oi; pos = op; }
                }
                const float minval = __shfl(v, 0);
                const int   minpos = __shfl(pos, 0);
                if (cv > minval) {   // strictly greater: keeps earliest index on ties
                    if (lane == 0) { topv[lr][minpos] = cv; topi[lr][minpos] = cj; }
                    float nv = (lane < KNN) ? ((lane == minpos) ? cv : topv[lr][lane])
                                            : __builtin_inff();
                    #pragma unroll
                    for (int off = 32; off; off >>= 1)
                        nv = fminf(nv, __shfl_down(nv, off));
                    if (lane == 0) minv[lr] = nv;
                }
            }
        }
        __syncthreads();   // done with scores before next staging overwrites xjT
    }

    for (int e = t; e < TI * KNN; e += 256)
        topIdx[(size_t)(rowBase + (e >> 5)) * KNN + (e & 31)] = topi[e >> 5][e & 31];
}

// ---------------- gather + MLP + pool + out ----------------
// h_k = A @ nbr_k + B @ x_self; pooled = mean_k clip(h_k); out = [pooled, x] @ W2^T
// AT is staged twice: first with B^T (for hself), then with A^T (for the main loop).
template<int D, int LAYER, int RPB, int NT>
__global__ __launch_bounds__(NT)
void mlp_kernel(const float* __restrict__ X, const int* __restrict__ topIdx,
                const float* __restrict__ W, const float* __restrict__ W2,
                float* __restrict__ out) {
    static_assert(NT == RPB * HDIM, "hself mapping");
    static_assert(NT / 32 == RPB * 4, "main-loop mapping");
    constexpr int W2C = HDIM + D;
    __shared__ float AT[D][HDIM + 4];        // holds B^T, then A^T
    __shared__ float nbrBuf[RPB * D * 36];   // gathered neighbors, transposed
    __shared__ float xi[RPB][D];
    __shared__ float hself[RPB][HDIM];
    __shared__ float part[RPB][4][HDIM];     // deterministic pooling partials
    __shared__ int   idx_s[RPB][KNN];

    const int t = threadIdx.x;
    const int rowBase = blockIdx.x * RPB;

    // phase 1: stage B^T into AT, plus xi and neighbor indices
    for (int e = t; e < HDIM * D; e += NT) {
        const int hh = e / D, d = e % D;
        AT[d][hh] = W[(size_t)hh * (2 * D) + D + d];   // B = W[:, D:2D]
    }
    for (int e = t; e < RPB * D; e += NT)
        xi[e / D][e % D] = X[(size_t)(rowBase + e / D) * D + (e % D)];
    if (t < RPB * KNN)
        idx_s[t >> 5][t & 31] = topIdx[(size_t)(rowBase + (t >> 5)) * KNN + (t & 31)];
    __syncthreads();

    {   // phase 2: hself = B @ x_self (RPB rows x 128 hh across NT threads)
        const int row = t / HDIM, hh = t % HDIM;
        float s = 0.f;
        #pragma unroll 4
        for (int d = 0; d < D; ++d)
            s = fmaf(AT[d][hh], xi[row][d], s);
        hself[row][hh] = s;
    }
    __syncthreads();   // everyone done reading AT-as-B^T

    // phase 3: restage A^T into AT, and gather neighbors transposed
    for (int e = t; e < HDIM * D; e += NT) {
        const int hh = e / D, d = e % D;
        AT[d][hh] = W[(size_t)hh * (2 * D) + d];       // A = W[:, 0:D]
    }
    for (int e = t; e < RPB * KNN * D; e += NT) {
        const int row = e / (KNN * D);
        const int rem = e % (KNN * D);
        const int k = rem / D, d = rem % D;
        nbrBuf[(row * D + d) * 36 + k] = X[(size_t)idx_s[row][k] * D + d];
    }
    __syncthreads();

    // phase 4: h = A @ nbr + hself, clip, pool
    const int hh4 = (t & 31) * 4;
    const int g   = t >> 5;
    const int row = g >> 2;
    const int k8  = (g & 3) * 8;
    float acc[4][8];
    #pragma unroll
    for (int q = 0; q < 4; ++q)
        #pragma unroll
        for (int r = 0; r < 8; ++r) acc[q][r] = 0.f;

    #pragma unroll 2
    for (int d = 0; d < D; ++d) {
        const float4 av = *reinterpret_cast<const float4*>(&AT[d][hh4]);
        const float4 b0 = *reinterpret_cast<const float4*>(&nbrBuf[(row * D + d) * 36 + k8]);
        const float4 b1 = *reinterpret_cast<const float4*>(&nbrBuf[(row * D + d) * 36 + k8 + 4]);
        const float aq[4] = {av.x, av.y, av.z, av.w};
        const float br[8] = {b0.x, b0.y, b0.z, b0.w, b1.x, b1.y, b1.z, b1.w};
        #pragma unroll
        for (int q = 0; q < 4; ++q)
            #pragma unroll
            for (int r = 0; r < 8; ++r)
                acc[q][r] = fmaf(aq[q], br[r], acc[q][r]);
    }

    #pragma unroll
    for (int q = 0; q < 4; ++q) {
        const float hs = hself[row][hh4 + q];
        float p = 0.f;
        #pragma unroll
        for (int r = 0; r < 8; ++r)
            p += fminf(1.f, fmaxf(-1.f, acc[q][r] + hs));
        part[row][g & 3][hh4 + q] = p * (1.f / KNN);
    }
    __syncthreads();

    // phase 5: out = [pooled, x] @ W2^T
    if (t < RPB * ODIM) {
        const int orow = t >> 6, o = t & 63;
        float s = 0.f;
        #pragma unroll 4
        for (int c = 0; c < HDIM; ++c) {
            const float pc = part[orow][0][c] + part[orow][1][c]
                           + part[orow][2][c] + part[orow][3][c];
            s = fmaf(pc, W2[(size_t)o * W2C + c], s);
        }
        #pragma unroll 4
        for (int d = 0; d < D; ++d)
            s = fmaf(xi[orow][d], W2[(size_t)o * W2C + HDIM + d], s);
        if (LAYER == 0)
            out[(size_t)(rowBase + orow) * 128 + 64 + o] = s;   // x1 cols 64..127
        else
            out[(size_t)(rowBase + orow) * ODIM + o] = s;       // final output
    }
    if (LAYER == 0 && t < RPB * 64) {
        const int orow = t >> 6, d = t & 63;
        out[(size_t)(rowBase + orow) * 128 + d] = xi[orow][d];  // x1 cols 0..63
    }
}

extern "C" void kernel_launch(void* const* d_in, const int* in_sizes, int n_in,
                              void* d_out, int out_size, void* d_ws, size_t ws_size,
                              hipStream_t stream) {
    const float* x    = (const float*)d_in[0];
    const float* w0   = (const float*)d_in[1];
    const float* w2_0 = (const float*)d_in[2];
    const float* w1   = (const float*)d_in[3];
    const float* w2_1 = (const float*)d_in[4];
    float* out = (float*)d_out;

    char* ws = (char*)d_ws;
    float* sq  = (float*)ws;                                     // NP floats
    int*   idx = (int*)(ws + (size_t)NP * 4);                    // NP*32 ints
    float* x1  = (float*)(ws + (size_t)NP * 4 + (size_t)NP * KNN * 4);  // NP*128 floats

    // layer 0 (D = 64)
    sq_kernel<64><<<NP / 4, 256, 0, stream>>>(x, sq);
    topk_kernel<64><<<NP / 64, 256, 0, stream>>>(x, sq, idx);
    mlp_kernel<64, 0, 4, 512><<<NP / 4, 512, 0, stream>>>(x, idx, w0, w2_0, x1);

    // layer 1 (D = 128, x1 = [x, o0])
    sq_kernel<128><<<NP / 4, 256, 0, stream>>>(x1, sq);
    topk_kernel<128><<<NP / 64, 256, 0, stream>>>(x1, sq, idx);
    mlp_kernel<128, 1, 2, 256><<<NP / 2, 256, 0, stream>>>(x1, idx, w1, w2_1, out);
}

// Round 4
// 8268.200 us; speedup vs baseline: 1.5488x; 1.5488x over previous
//
#include <hip/hip_runtime.h>

#define NP   16384
#define KNN  32
#define HDIM 128
#define ODIM 64

// ---------------- squared norms ----------------
template<int D>
__global__ __launch_bounds__(256)
void sq_kernel(const float* __restrict__ X, float* __restrict__ sq) {
    const int lane = threadIdx.x & 63;
    const int row  = blockIdx.x * 4 + (threadIdx.x >> 6);
    float s = 0.f;
    #pragma unroll
    for (int d = lane; d < D; d += 64) {
        const float v = X[(size_t)row * D + d];
        s = fmaf(v, v, s);
    }
    #pragma unroll
    for (int off = 32; off; off >>= 1) s += __shfl_down(s, off);
    if (lane == 0) sq[row] = s;
}

// ---------------- top-32 neighbors (streaming) ----------------
// score_j = dot(x_i, x_j) - 0.5*sq_j  (argmax score == argmin d2 per row)
// 512 threads, TI=64 rows/block, JC=128 cols/tile, 4x4 thread score tiles.
// Register prefetch of next tile (issue loads before GEMM, write after barrier).
template<int D>
__global__ __launch_bounds__(512)
void topk_kernel(const float* __restrict__ X, const float* __restrict__ sq,
                 int* __restrict__ topIdx) {
    constexpr int TI = 64, JC = 128;
    constexpr int NTILES = NP / JC;
    constexpr int NSTG = JC * D / 4 / 512;   // float4s per thread per j-tile
    constexpr int NSTI = TI * D / 4 / 512;   // float4s per thread for xi
    constexpr int SS = TI + 1;               // scoresT row stride (odd, scalar access)

    __shared__ float xiT[D * TI];            // [d][i], stride TI
    __shared__ float xjT[D * JC];            // [d][j], stride JC
    __shared__ float scoresT[JC * SS];       // [col][row], wave-private rows
    __shared__ float sqj[JC];
    __shared__ float topv[TI * KNN];
    __shared__ int   topi[TI * KNN];
    __shared__ float minv[TI];

    const int t = threadIdx.x;
    const int rowBase = blockIdx.x * TI;
    const int lane = t & 63, wave = t >> 6;
    const int ti = t >> 5, tj = t & 31;      // ti: 16 row-groups, tj: 32 col-groups
    const int i4 = ti * 4, j4 = tj * 4;      // wave w owns score rows [8w, 8w+8)

    // stage xi transposed: i-fastest lanes -> conflict-free LDS writes
    #pragma unroll
    for (int s = 0; s < NSTI; ++s) {
        const int idx = s * 512 + t;
        const int i = idx & 63, dg = idx >> 6;
        const float4 v = *reinterpret_cast<const float4*>(
            X + (size_t)(rowBase + i) * D + 4 * dg);
        xiT[(4 * dg + 0) * TI + i] = v.x; xiT[(4 * dg + 1) * TI + i] = v.y;
        xiT[(4 * dg + 2) * TI + i] = v.z; xiT[(4 * dg + 3) * TI + i] = v.w;
    }
    for (int e = t; e < TI * KNN; e += 512) {
        topv[e] = -__builtin_inff();
        topi[e] = 0;
    }
    if (t < TI) minv[t] = -__builtin_inff();

    // prologue: load tile 0 into regs
    float4 stg[NSTG];
    float  sqstg = 0.f;
    #pragma unroll
    for (int s = 0; s < NSTG; ++s) {
        const int idx = s * 512 + t;
        const int j = idx & (JC - 1), dg = idx >> 7;
        stg[s] = *reinterpret_cast<const float4*>(X + (size_t)j * D + 4 * dg);
    }
    if (t < JC) sqstg = sq[t];
    __syncthreads();
    #pragma unroll
    for (int s = 0; s < NSTG; ++s) {
        const int idx = s * 512 + t;
        const int j = idx & (JC - 1), dg = idx >> 7;
        xjT[(4 * dg + 0) * JC + j] = stg[s].x; xjT[(4 * dg + 1) * JC + j] = stg[s].y;
        xjT[(4 * dg + 2) * JC + j] = stg[s].z; xjT[(4 * dg + 3) * JC + j] = stg[s].w;
    }
    if (t < JC) sqj[t] = sqstg;
    __syncthreads();

    for (int it = 0; it < NTILES; ++it) {
        const int jb = it * JC;
        // issue next-tile loads early (latency hides under GEMM)
        if (it + 1 < NTILES) {
            const int jb2 = jb + JC;
            #pragma unroll
            for (int s = 0; s < NSTG; ++s) {
                const int idx = s * 512 + t;
                const int j = idx & (JC - 1), dg = idx >> 7;
                stg[s] = *reinterpret_cast<const float4*>(
                    X + (size_t)(jb2 + j) * D + 4 * dg);
            }
            if (t < JC) sqstg = sq[jb2 + t];
        }

        // GEMM: 4x4 scores per thread
        float acc[4][4];
        #pragma unroll
        for (int a = 0; a < 4; ++a)
            #pragma unroll
            for (int b = 0; b < 4; ++b) acc[a][b] = 0.f;

        #pragma unroll 4
        for (int d = 0; d < D; ++d) {
            const float4 xv = *reinterpret_cast<const float4*>(&xiT[d * TI + i4]);
            const float4 yv = *reinterpret_cast<const float4*>(&xjT[d * JC + j4]);
            const float xa[4] = {xv.x, xv.y, xv.z, xv.w};
            const float xb[4] = {yv.x, yv.y, yv.z, yv.w};
            #pragma unroll
            for (int a = 0; a < 4; ++a)
                #pragma unroll
                for (int b = 0; b < 4; ++b)
                    acc[a][b] = fmaf(xa[a], xb[b], acc[a][b]);
        }

        // score write (wave-private rows, scalar stores, no barrier needed)
        #pragma unroll
        for (int b = 0; b < 4; ++b) {
            const float sc = -0.5f * sqj[j4 + b];
            #pragma unroll
            for (int a = 0; a < 4; ++a)
                scoresT[(j4 + b) * SS + i4 + a] = acc[a][b] + sc;
        }

        // streaming top-k: wave owns rows [8*wave, 8*wave+8)
        #pragma unroll 1
        for (int r = 0; r < 8; ++r) {
            const int lr = wave * 8 + r;
            #pragma unroll 1
            for (int h = 0; h < 2; ++h) {      // ascending j halves => stable ties
                const float sv = scoresT[(h * 64 + lane) * SS + lr];
                const float mv = minv[lr];
                unsigned long long mask = __ballot(sv > mv);
                while (mask) {
                    const int l = __builtin_ctzll(mask);
                    mask &= mask - 1;
                    const float cv = __shfl(sv, l);
                    const int   cj = jb + h * 64 + l;
                    float v  = (lane < KNN) ? topv[lr * KNN + lane] : __builtin_inff();
                    int   si = (lane < KNN) ? topi[lr * KNN + lane] : 0x7fffffff;
                    int   pos = lane;
                    #pragma unroll
                    for (int off = 32; off; off >>= 1) {
                        const float ov = __shfl_down(v, off);
                        const int   oi = __shfl_down(si, off);
                        const int   op = __shfl_down(pos, off);
                        if (ov < v || (ov == v && oi > si)) { v = ov; si = oi; pos = op; }
                    }
                    const float minval = __shfl(v, 0);
                    const int   minpos = __shfl(pos, 0);
                    if (cv > minval) {   // strictly greater: earliest index wins ties
                        if (lane == 0) {
                            topv[lr * KNN + minpos] = cv;
                            topi[lr * KNN + minpos] = cj;
                        }
                        float nv = (lane < KNN)
                            ? ((lane == minpos) ? cv : topv[lr * KNN + lane])
                            : __builtin_inff();
                        #pragma unroll
                        for (int off = 32; off; off >>= 1)
                            nv = fminf(nv, __shfl_down(nv, off));
                        if (lane == 0) minv[lr] = nv;
                    }
                }
            }
        }
        __syncthreads();   // all waves done with xjT/sqj
        if (it + 1 < NTILES) {
            #pragma unroll
            for (int s = 0; s < NSTG; ++s) {
                const int idx = s * 512 + t;
                const int j = idx & (JC - 1), dg = idx >> 7;
                xjT[(4 * dg + 0) * JC + j] = stg[s].x;
                xjT[(4 * dg + 1) * JC + j] = stg[s].y;
                xjT[(4 * dg + 2) * JC + j] = stg[s].z;
                xjT[(4 * dg + 3) * JC + j] = stg[s].w;
            }
            if (t < JC) sqj[t] = sqstg;
        }
        __syncthreads();
    }

    for (int e = t; e < TI * KNN; e += 512)
        topIdx[(size_t)(rowBase + (e >> 5)) * KNN + (e & 31)] = topi[e];
}

// ---------------- gather + MLP + pool + out ----------------
// h_k = A @ nbr_k + B @ x_self; pooled = mean_k clip(h_k); out = [pooled, x] @ W2^T
// A/B staged row-major with odd stride 129 (free staging writes); nbr stride 36.
template<int D, int LAYER, int RPB, int KG, int KPT>
__global__ __launch_bounds__(512)
void mlp_kernel(const float* __restrict__ X, const int* __restrict__ topIdx,
                const float* __restrict__ W, const float* __restrict__ W2,
                float* __restrict__ out) {
    static_assert(RPB * KG == 16, "main-loop groups");
    static_assert(KG * KPT == KNN, "k coverage");
    constexpr int W2C = HDIM + D;
    constexpr int AS = D + 1;                 // odd stride for A rows
    constexpr int NBS = 36;                   // nbr k-stride (multiple of 4)
    __shared__ float A_s[HDIM * AS];          // holds B row-major, then A row-major
    __shared__ float nbrBuf[RPB * D * NBS];   // [row][d][k]
    __shared__ float xi[RPB][D];
    __shared__ float hself[RPB][HDIM];
    __shared__ float part[RPB][KG][HDIM];
    __shared__ int   idx_s[RPB][KNN];

    const int t = threadIdx.x;
    const int rowBase = blockIdx.x * RPB;

    // phase 1: stage B row-major (d-fastest: coalesced global, free LDS writes)
    for (int e = t; e < HDIM * D; e += 512) {
        const int hh = e / D, d = e % D;
        A_s[hh * AS + d] = W[(size_t)hh * (2 * D) + D + d];   // B = W[:, D:2D]
    }
    for (int e = t; e < RPB * D; e += 512)
        xi[e / D][e % D] = X[(size_t)(rowBase + e / D) * D + (e % D)];
    if (t < RPB * KNN)
        idx_s[t >> 5][t & 31] = topIdx[(size_t)(rowBase + (t >> 5)) * KNN + (t & 31)];
    __syncthreads();

    // phase 2: hself = B @ x_self
    if (t < RPB * HDIM) {
        const int row = t / HDIM, hh = t % HDIM;
        float s = 0.f;
        #pragma unroll 4
        for (int d = 0; d < D; ++d)
            s = fmaf(A_s[hh * AS + d], xi[row][d], s);
        hself[row][hh] = s;
    }
    __syncthreads();

    // phase 3: restage A; gather neighbors (float4, coalesced)
    for (int e = t; e < HDIM * D; e += 512) {
        const int hh = e / D, d = e % D;
        A_s[hh * AS + d] = W[(size_t)hh * (2 * D) + d];       // A = W[:, 0:D]
    }
    constexpr int RC4 = KNN * D / 4;
    for (int e4 = t; e4 < RPB * RC4; e4 += 512) {
        const int row = e4 / RC4;
        const int r4  = e4 % RC4;
        const int k   = r4 / (D / 4);
        const int d4  = (r4 % (D / 4)) * 4;
        const float4 v = *reinterpret_cast<const float4*>(
            X + (size_t)idx_s[row][k] * D + d4);
        nbrBuf[(row * D + d4 + 0) * NBS + k] = v.x;
        nbrBuf[(row * D + d4 + 1) * NBS + k] = v.y;
        nbrBuf[(row * D + d4 + 2) * NBS + k] = v.z;
        nbrBuf[(row * D + d4 + 3) * NBS + k] = v.w;
    }
    __syncthreads();

    // phase 4: h = A @ nbr + hself, clip, pool partials
    const int hh4 = (t & 31) * 4;
    const int g   = t >> 5;
    const int row = g / KG;
    const int kb  = (g % KG) * KPT;
    float acc[4][KPT];
    #pragma unroll
    for (int q = 0; q < 4; ++q)
        #pragma unroll
        for (int r = 0; r < KPT; ++r) acc[q][r] = 0.f;

    #pragma unroll 2
    for (int d = 0; d < D; ++d) {
        float aq[4];
        #pragma unroll
        for (int q = 0; q < 4; ++q) aq[q] = A_s[(hh4 + q) * AS + d];
        float br[KPT];
        #pragma unroll
        for (int c = 0; c < KPT / 4; ++c) {
            const float4 bv = *reinterpret_cast<const float4*>(
                &nbrBuf[(row * D + d) * NBS + kb + 4 * c]);
            br[4 * c + 0] = bv.x; br[4 * c + 1] = bv.y;
            br[4 * c + 2] = bv.z; br[4 * c + 3] = bv.w;
        }
        #pragma unroll
        for (int q = 0; q < 4; ++q)
            #pragma unroll
            for (int r = 0; r < KPT; ++r)
                acc[q][r] = fmaf(aq[q], br[r], acc[q][r]);
    }

    #pragma unroll
    for (int q = 0; q < 4; ++q) {
        const float hs = hself[row][hh4 + q];
        float p = 0.f;
        #pragma unroll
        for (int r = 0; r < KPT; ++r)
            p += fminf(1.f, fmaxf(-1.f, acc[q][r] + hs));
        part[row][g % KG][hh4 + q] = p * (1.f / KNN);
    }
    __syncthreads();

    // phase 5: out = [pooled, x] @ W2^T
    if (t < RPB * ODIM) {
        const int orow = t >> 6, o = t & 63;
        float s = 0.f;
        #pragma unroll 4
        for (int c = 0; c < HDIM; ++c) {
            float pc = 0.f;
            #pragma unroll
            for (int i = 0; i < KG; ++i) pc += part[orow][i][c];
            s = fmaf(pc, W2[(size_t)o * W2C + c], s);
        }
        #pragma unroll 4
        for (int d = 0; d < D; ++d)
            s = fmaf(xi[orow][d], W2[(size_t)o * W2C + HDIM + d], s);
        if (LAYER == 0)
            out[(size_t)(rowBase + orow) * 128 + 64 + o] = s;   // x1 cols 64..127
        else
            out[(size_t)(rowBase + orow) * ODIM + o] = s;       // final output
    }
    if (LAYER == 0 && t < RPB * 64) {
        const int orow = t >> 6, d = t & 63;
        out[(size_t)(rowBase + orow) * 128 + d] = xi[orow][d];  // x1 cols 0..63
    }
}

extern "C" void kernel_launch(void* const* d_in, const int* in_sizes, int n_in,
                              void* d_out, int out_size, void* d_ws, size_t ws_size,
                              hipStream_t stream) {
    const float* x    = (const float*)d_in[0];
    const float* w0   = (const float*)d_in[1];
    const float* w2_0 = (const float*)d_in[2];
    const float* w1   = (const float*)d_in[3];
    const float* w2_1 = (const float*)d_in[4];
    float* out = (float*)d_out;

    char* ws = (char*)d_ws;
    float* sq  = (float*)ws;                                     // NP floats
    int*   idx = (int*)(ws + (size_t)NP * 4);                    // NP*32 ints
    float* x1  = (float*)(ws + (size_t)NP * 4 + (size_t)NP * KNN * 4);  // NP*128 floats

    // layer 0 (D = 64)
    sq_kernel<64><<<NP / 4, 256, 0, stream>>>(x, sq);
    topk_kernel<64><<<NP / 64, 512, 0, stream>>>(x, sq, idx);
    mlp_kernel<64, 0, 4, 4, 8><<<NP / 4, 512, 0, stream>>>(x, idx, w0, w2_0, x1);

    // layer 1 (D = 128, x1 = [x, o0])
    sq_kernel<128><<<NP / 4, 256, 0, stream>>>(x1, sq);
    topk_kernel<128><<<NP / 64, 512, 0, stream>>>(x1, sq, idx);
    mlp_kernel<128, 1, 2, 8, 4><<<NP / 2, 512, 0, stream>>>(x1, idx, w1, w2_1, out);
}

// Round 5
// 5952.851 us; speedup vs baseline: 2.1512x; 1.3889x over previous
//
#include <hip/hip_runtime.h>

#define NP   16384
#define KNN  32
#define HDIM 128
#define ODIM 64

// ---------------- squared norms ----------------
template<int D>
__global__ __launch_bounds__(256)
void sq_kernel(const float* __restrict__ X, float* __restrict__ sq) {
    const int lane = threadIdx.x & 63;
    const int row  = blockIdx.x * 4 + (threadIdx.x >> 6);
    float s = 0.f;
    #pragma unroll
    for (int d = lane; d < D; d += 64) {
        const float v = X[(size_t)row * D + d];
        s = fmaf(v, v, s);
    }
    #pragma unroll
    for (int off = 32; off; off >>= 1) s += __shfl_down(s, off);
    if (lane == 0) sq[row] = s;
}

// ---------------- top-32 neighbors (streaming, register top-k) ----------------
// score_j = dot(x_i,x_j) - 0.5*sq_j (argmax score == argmin d2 per row).
// 512 thr = 8 waves; wave owns 8 rows; lane owns cols {lane, lane+64} of a
// 128-col tile -> scores stay in regs, scan is pure shuffle/ballot.
template<int D>
__global__ __launch_bounds__(512)
void topk_kernel(const float* __restrict__ X, const float* __restrict__ sq,
                 int* __restrict__ topIdx) {
    constexpr int TI = 64, JC = 128;
    constexpr int NT = NP / JC;
    constexpr int NSTG = JC * D / 4 / 512;   // float4/thread per j-tile
    constexpr int NSTI = TI * D / 4 / 512;   // float4/thread for xi
    __shared__ float xi_s[D * TI];           // [d][i]
    __shared__ float xjT[D * JC];            // [d][j]
    __shared__ float sqj[JC];

    const int t = threadIdx.x;
    const int lane = t & 63, wave = t >> 6;
    const int rowBase = blockIdx.x * TI;
    const int xiOff = wave * 8;
    const float INF = __builtin_inff();

    float tv[8]; int tidx[8]; float minv[8];
    #pragma unroll
    for (int r = 0; r < 8; ++r) { tv[r] = -INF; tidx[r] = 0; minv[r] = -INF; }

    // stage xi transposed (i-fastest lanes -> conflict-free writes)
    #pragma unroll
    for (int s = 0; s < NSTI; ++s) {
        const int e = s * 512 + t;
        const int i = e & 63, dg = e >> 6;
        const float4 v = *reinterpret_cast<const float4*>(
            X + (size_t)(rowBase + i) * D + 4 * dg);
        xi_s[(4 * dg + 0) * TI + i] = v.x; xi_s[(4 * dg + 1) * TI + i] = v.y;
        xi_s[(4 * dg + 2) * TI + i] = v.z; xi_s[(4 * dg + 3) * TI + i] = v.w;
    }

    float4 stg[NSTG];
    float  sqstg = 0.f;
    #pragma unroll
    for (int s = 0; s < NSTG; ++s) {
        const int e = s * 512 + t;
        const int j = e & (JC - 1), dg = e >> 7;
        stg[s] = *reinterpret_cast<const float4*>(X + (size_t)j * D + 4 * dg);
    }
    if (t < JC) sqstg = sq[t];
    __syncthreads();
    #pragma unroll
    for (int s = 0; s < NSTG; ++s) {
        const int e = s * 512 + t;
        const int j = e & (JC - 1), dg = e >> 7;
        xjT[(4 * dg + 0) * JC + j] = stg[s].x; xjT[(4 * dg + 1) * JC + j] = stg[s].y;
        xjT[(4 * dg + 2) * JC + j] = stg[s].z; xjT[(4 * dg + 3) * JC + j] = stg[s].w;
    }
    if (t < JC) sqj[t] = sqstg;
    __syncthreads();
    // prefetch tile 1
    #pragma unroll
    for (int s = 0; s < NSTG; ++s) {
        const int e = s * 512 + t;
        const int j = e & (JC - 1), dg = e >> 7;
        stg[s] = *reinterpret_cast<const float4*>(X + (size_t)(JC + j) * D + 4 * dg);
    }
    if (t < JC) sqstg = sq[JC + t];

    for (int it = 0; it < NT; ++it) {
        // GEMM: 8 rows (broadcast) x 2 cols (per-lane)
        float acc0[8], acc1[8];
        #pragma unroll
        for (int r = 0; r < 8; ++r) { acc0[r] = 0.f; acc1[r] = 0.f; }
        #pragma unroll 4
        for (int d = 0; d < D; ++d) {
            const float4 a0 = *reinterpret_cast<const float4*>(&xi_s[d * TI + xiOff]);
            const float4 a1 = *reinterpret_cast<const float4*>(&xi_s[d * TI + xiOff + 4]);
            const float b0 = xjT[d * JC + lane];
            const float b1 = xjT[d * JC + 64 + lane];
            acc0[0] = fmaf(a0.x, b0, acc0[0]); acc1[0] = fmaf(a0.x, b1, acc1[0]);
            acc0[1] = fmaf(a0.y, b0, acc0[1]); acc1[1] = fmaf(a0.y, b1, acc1[1]);
            acc0[2] = fmaf(a0.z, b0, acc0[2]); acc1[2] = fmaf(a0.z, b1, acc1[2]);
            acc0[3] = fmaf(a0.w, b0, acc0[3]); acc1[3] = fmaf(a0.w, b1, acc1[3]);
            acc0[4] = fmaf(a1.x, b0, acc0[4]); acc1[4] = fmaf(a1.x, b1, acc1[4]);
            acc0[5] = fmaf(a1.y, b0, acc0[5]); acc1[5] = fmaf(a1.y, b1, acc1[5]);
            acc0[6] = fmaf(a1.z, b0, acc0[6]); acc1[6] = fmaf(a1.z, b1, acc1[6]);
            acc0[7] = fmaf(a1.w, b0, acc0[7]); acc1[7] = fmaf(a1.w, b1, acc1[7]);
        }
        const float sub0 = 0.5f * sqj[lane];
        const float sub1 = 0.5f * sqj[64 + lane];
        __syncthreads();                       // reads of xjT/sqj done
        if (it + 1 < NT) {
            #pragma unroll
            for (int s = 0; s < NSTG; ++s) {
                const int e = s * 512 + t;
                const int j = e & (JC - 1), dg = e >> 7;
                xjT[(4 * dg + 0) * JC + j] = stg[s].x;
                xjT[(4 * dg + 1) * JC + j] = stg[s].y;
                xjT[(4 * dg + 2) * JC + j] = stg[s].z;
                xjT[(4 * dg + 3) * JC + j] = stg[s].w;
            }
            if (t < JC) sqj[t] = sqstg;
        }
        __syncthreads();                       // next tile staged
        if (it + 2 < NT) {
            const int jb2 = (it + 2) * JC;
            #pragma unroll
            for (int s = 0; s < NSTG; ++s) {
                const int e = s * 512 + t;
                const int j = e & (JC - 1), dg = e >> 7;
                stg[s] = *reinterpret_cast<const float4*>(
                    X + (size_t)(jb2 + j) * D + 4 * dg);
            }
            if (t < JC) sqstg = sq[jb2 + t];
        }

        // scan (pure VALU/shuffle; hides the global prefetch latency)
        #pragma unroll
        for (int r = 0; r < 8; ++r) {
            if (it == 0) {                     // seed from cols 0..31
                const float s0 = acc0[r] - sub0;
                tv[r] = s0;
                tidx[r] = lane;
                float m = (lane < KNN) ? s0 : INF;
                #pragma unroll
                for (int off = 32; off; off >>= 1) m = fminf(m, __shfl_down(m, off));
                minv[r] = __shfl(m, 0);
            }
            #pragma unroll
            for (int h = 0; h < 2; ++h) {
                const float sv = (h ? acc1[r] : acc0[r]) - (h ? sub1 : sub0);
                unsigned long long mask = __ballot(sv > minv[r]);
                if (it == 0 && h == 0) mask &= 0xFFFFFFFF00000000ULL;  // seeded
                while (mask) {
                    const int l = __builtin_ctzll(mask);  // ascending j => stable
                    mask &= mask - 1;
                    const float cv = __shfl(sv, l);
                    if (!(cv > minv[r])) continue;
                    const int cj = it * JC + h * 64 + l;
                    // one pass: min (value, tie->larger idx evicted), pos, 2nd-min
                    float v  = (lane < KNN) ? tv[r] : INF;
                    int   si = (lane < KNN) ? tidx[r] : 0x7fffffff;
                    int   pos = lane;
                    float v2 = INF;
                    #pragma unroll
                    for (int off = 32; off; off >>= 1) {
                        const float ov  = __shfl_down(v, off);
                        const int   oi  = __shfl_down(si, off);
                        const int   op  = __shfl_down(pos, off);
                        const float ov2 = __shfl_down(v2, off);
                        const float rest = fminf(v2, ov2);
                        const bool take = (ov < v) || (ov == v && oi > si);
                        v2 = fminf(rest, take ? v : ov);
                        if (take) { v = ov; si = oi; pos = op; }
                    }
                    const float minval = __shfl(v, 0);
                    const int   minpos = __shfl(pos, 0);
                    const float min2   = __shfl(v2, 0);
                    if (cv > minval) {
                        if (lane == minpos) { tv[r] = cv; tidx[r] = cj; }
                        minv[r] = fminf(min2, cv);  // uniform
                    }
                }
            }
        }
    }

    if (lane < KNN) {
        #pragma unroll
        for (int r = 0; r < 8; ++r)
            topIdx[(size_t)(rowBase + wave * 8 + r) * KNN + lane] = tidx[r];
    }
}

// ---------------- gather + MLP + pool + out ----------------
// h_k = A@nbr_k + B@x; pooled = mean_k clip(h_k); out = [pooled, x] @ W2^T.
// A transposed in LDS ([d][hh], b128 reads); B@x read straight from global;
// phases: {xi,idx} -> {A-stage || gather || hself} -> {GEMM+pool} -> {out}.
template<int D, int LAYER, int RPB, int KG, int KPT>
__global__ __launch_bounds__(512)
void mlp_kernel(const float* __restrict__ X, const int* __restrict__ topIdx,
                const float* __restrict__ W, const float* __restrict__ W2,
                float* __restrict__ out) {
    static_assert(RPB * KG == 16, "phase-2 groups");
    static_assert(KG * KPT == KNN, "k coverage");
    constexpr int W2C  = HDIM + D;
    constexpr int AS2  = HDIM + 4;             // AT row stride
    constexpr int NBS  = 36;                   // nbr k-stride
    constexpr int SPL  = 512 / (RPB * HDIM);   // hself d-split (1 or 2)
    constexpr int DL   = D / SPL;
    constexpr int SPL2 = 512 / (RPB * ODIM);   // out col-split (2 or 4)
    constexpr int CL   = W2C / SPL2;
    __shared__ float AT[D * AS2];              // A^T: [d][hh]
    __shared__ float nbr[RPB * D * NBS];       // [row][d][k]
    __shared__ float xi[RPB][D];
    __shared__ float hs_s[RPB][HDIM][SPL];
    __shared__ float part[RPB][KG][HDIM];
    __shared__ int   idx_s[RPB][KNN];

    const int t = threadIdx.x;
    const int rowBase = blockIdx.x * RPB;

    // phase 0: xi + neighbor indices (tiny)
    if (t < RPB * D / 4) {
        const int i = t / (D / 4), dg = t % (D / 4);
        const float4 v = *reinterpret_cast<const float4*>(
            X + (size_t)(rowBase + i) * D + 4 * dg);
        xi[i][4 * dg + 0] = v.x; xi[i][4 * dg + 1] = v.y;
        xi[i][4 * dg + 2] = v.z; xi[i][4 * dg + 3] = v.w;
    }
    if (t < RPB * KNN)
        idx_s[t >> 5][t & 31] = topIdx[(size_t)(rowBase + (t >> 5)) * KNN + (t & 31)];
    __syncthreads();

    // phase 1: A^T stage || neighbor gather || hself = B @ x (B from global)
    for (int e = t; e < HDIM * D / 4; e += 512) {
        const int hh = e % HDIM, dg = e / HDIM;
        const float4 v = *reinterpret_cast<const float4*>(
            W + (size_t)hh * (2 * D) + 4 * dg);
        AT[(4 * dg + 0) * AS2 + hh] = v.x; AT[(4 * dg + 1) * AS2 + hh] = v.y;
        AT[(4 * dg + 2) * AS2 + hh] = v.z; AT[(4 * dg + 3) * AS2 + hh] = v.w;
    }
    constexpr int RC4 = KNN * D / 4;
    for (int e4 = t; e4 < RPB * RC4; e4 += 512) {
        const int row = e4 / RC4;
        const int r4  = e4 % RC4;
        const int k   = r4 / (D / 4);
        const int d4  = (r4 % (D / 4)) * 4;
        const float4 v = *reinterpret_cast<const float4*>(
            X + (size_t)idx_s[row][k] * D + d4);
        nbr[(row * D + d4 + 0) * NBS + k] = v.x;
        nbr[(row * D + d4 + 1) * NBS + k] = v.y;
        nbr[(row * D + d4 + 2) * NBS + k] = v.z;
        nbr[(row * D + d4 + 3) * NBS + k] = v.w;
    }
    {
        const int hr = t / (HDIM * SPL);
        const int hh = (t / SPL) % HDIM;
        const int hf = t % SPL;
        const float* wb = W + (size_t)hh * (2 * D) + D + hf * DL;
        float s = 0.f;
        #pragma unroll 8
        for (int d = 0; d < DL; ++d)
            s = fmaf(wb[d], xi[hr][hf * DL + d], s);
        hs_s[hr][hh][hf] = s;
    }
    __syncthreads();

    // phase 2: h = A@nbr + hself, clip, pool partials
    const int hh4 = (t & 31) * 4;
    const int g   = t >> 5;
    const int row = g / KG;
    const int kb  = (g % KG) * KPT;
    float acc[4][KPT];
    #pragma unroll
    for (int q = 0; q < 4; ++q)
        #pragma unroll
        for (int r = 0; r < KPT; ++r) acc[q][r] = 0.f;

    #pragma unroll 2
    for (int d = 0; d < D; ++d) {
        const float4 av = *reinterpret_cast<const float4*>(&AT[d * AS2 + hh4]);
        const float aq[4] = {av.x, av.y, av.z, av.w};
        float br[KPT];
        #pragma unroll
        for (int c = 0; c < KPT / 4; ++c) {
            const float4 bv = *reinterpret_cast<const float4*>(
                &nbr[(row * D + d) * NBS + kb + 4 * c]);
            br[4 * c + 0] = bv.x; br[4 * c + 1] = bv.y;
            br[4 * c + 2] = bv.z; br[4 * c + 3] = bv.w;
        }
        #pragma unroll
        for (int q = 0; q < 4; ++q)
            #pragma unroll
            for (int r = 0; r < KPT; ++r)
                acc[q][r] = fmaf(aq[q], br[r], acc[q][r]);
    }

    #pragma unroll
    for (int q = 0; q < 4; ++q) {
        float hs = hs_s[row][hh4 + q][0];
        if (SPL > 1) hs += hs_s[row][hh4 + q][SPL - 1];
        float p = 0.f;
        #pragma unroll
        for (int r = 0; r < KPT; ++r)
            p += fminf(1.f, fmaxf(-1.f, acc[q][r] + hs));
        part[row][g % KG][hh4 + q] = p * (1.f / KNN);
    }
    __syncthreads();

    // phase 3: out = [pooled, x] @ W2^T, split over SPL2 column chunks
    {
        const int og   = t / SPL2;
        const int spl  = t % SPL2;
        const int orow = og >> 6, o = og & 63;
        const int c0   = spl * CL;
        float s = 0.f;
        for (int c = c0; c < c0 + CL; ++c) {
            float vsrc;
            if (c < HDIM) {
                float pc = 0.f;
                #pragma unroll
                for (int i = 0; i < KG; ++i) pc += part[orow][i][c];
                vsrc = pc;
            } else {
                vsrc = xi[orow][c - HDIM];
            }
            s = fmaf(vsrc, W2[(size_t)o * W2C + c], s);
        }
        #pragma unroll
        for (int off = SPL2 / 2; off; off >>= 1) s += __shfl_down(s, off);
        if (spl == 0) {
            if (LAYER == 0)
                out[(size_t)(rowBase + orow) * 128 + 64 + o] = s;  // x1 cols 64..127
            else
                out[(size_t)(rowBase + orow) * ODIM + o] = s;      // final output
        }
    }
    if (LAYER == 0 && t < RPB * 64) {
        const int orow = t >> 6, d = t & 63;
        out[(size_t)(rowBase + orow) * 128 + d] = xi[orow][d];     // x1 cols 0..63
    }
}

extern "C" void kernel_launch(void* const* d_in, const int* in_sizes, int n_in,
                              void* d_out, int out_size, void* d_ws, size_t ws_size,
                              hipStream_t stream) {
    const float* x    = (const float*)d_in[0];
    const float* w0   = (const float*)d_in[1];
    const float* w2_0 = (const float*)d_in[2];
    const float* w1   = (const float*)d_in[3];
    const float* w2_1 = (const float*)d_in[4];
    float* out = (float*)d_out;

    char* ws = (char*)d_ws;
    float* sq  = (float*)ws;                                     // NP floats
    int*   idx = (int*)(ws + (size_t)NP * 4);                    // NP*32 ints
    float* x1  = (float*)(ws + (size_t)NP * 4 + (size_t)NP * KNN * 4);  // NP*128

    // layer 0 (D = 64)
    sq_kernel<64><<<NP / 4, 256, 0, stream>>>(x, sq);
    topk_kernel<64><<<NP / 64, 512, 0, stream>>>(x, sq, idx);
    mlp_kernel<64, 0, 4, 4, 8><<<NP / 4, 512, 0, stream>>>(x, idx, w0, w2_0, x1);

    // layer 1 (D = 128, x1 = [x, o0])
    sq_kernel<128><<<NP / 4, 256, 0, stream>>>(x1, sq);
    topk_kernel<128><<<NP / 64, 512, 0, stream>>>(x1, sq, idx);
    mlp_kernel<128, 1, 2, 8, 4><<<NP / 2, 512, 0, stream>>>(x1, idx, w1, w2_1, out);
}

// Round 6
// 5898.537 us; speedup vs baseline: 2.1710x; 1.0092x over previous
//
#include <hip/hip_runtime.h>

#define NP   16384
#define KNN  32
#define HDIM 128
#define ODIM 64

// ---------------- squared norms ----------------
template<int D>
__global__ __launch_bounds__(256)
void sq_kernel(const float* __restrict__ X, float* __restrict__ sq) {
    const int lane = threadIdx.x & 63;
    const int row  = blockIdx.x * 4 + (threadIdx.x >> 6);
    float s = 0.f;
    #pragma unroll
    for (int d = lane; d < D; d += 64) {
        const float v = X[(size_t)row * D + d];
        s = fmaf(v, v, s);
    }
    #pragma unroll
    for (int off = 32; off; off >>= 1) s += __shfl_down(s, off);
    if (lane == 0) sq[row] = s;
}

// ---------------- top-32 neighbors (streaming, register top-k) ----------------
// score_j = dot(x_i,x_j) - 0.5*sq_j (argmax score == argmin d2 per row).
// 8 waves; wave owns 8 rows (xi via uniform s_load -> SGPR broadcast operand);
// lane owns cols {lane, lane+64}; xj in LDS as [d-pair][j] float2 (b64, 2-way free).
template<int D>
__global__ __launch_bounds__(512)
void topk_kernel(const float* __restrict__ X, const float* __restrict__ sq,
                 int* __restrict__ topIdx) {
    constexpr int TI = 64, JC = 128;
    constexpr int NT = NP / JC;
    constexpr int NSTG = JC * D / 4 / 512;   // float4/thread per j-tile
    __shared__ float2 xjP[(D / 2) * JC];     // [pair p][j]: (d=2p, d=2p+1) of col j

    const int t = threadIdx.x;
    const int lane = t & 63;
    const int waveU = __builtin_amdgcn_readfirstlane(t >> 6);   // SGPR wave id
    const int rowBase = blockIdx.x * TI;
    const float* __restrict__ xr = X + (size_t)(rowBase + waveU * 8) * D;
    const float INF = __builtin_inff();

    float tv[8]; int tidx[8]; float minv[8];
    #pragma unroll
    for (int r = 0; r < 8; ++r) { tv[r] = -INF; tidx[r] = 0; minv[r] = -INF; }

    float4 stg[NSTG];
    // stage tile 0
    #pragma unroll
    for (int s = 0; s < NSTG; ++s) {
        const int e = s * 512 + t;
        const int j = e & (JC - 1), dg = e >> 7;
        stg[s] = *reinterpret_cast<const float4*>(X + (size_t)j * D + 4 * dg);
    }
    #pragma unroll
    for (int s = 0; s < NSTG; ++s) {
        const int e = s * 512 + t;
        const int j = e & (JC - 1), dg = e >> 7;
        xjP[(2 * dg + 0) * JC + j] = make_float2(stg[s].x, stg[s].y);
        xjP[(2 * dg + 1) * JC + j] = make_float2(stg[s].z, stg[s].w);
    }
    __syncthreads();
    // prefetch tile 1
    #pragma unroll
    for (int s = 0; s < NSTG; ++s) {
        const int e = s * 512 + t;
        const int j = e & (JC - 1), dg = e >> 7;
        stg[s] = *reinterpret_cast<const float4*>(X + (size_t)(JC + j) * D + 4 * dg);
    }

    for (int it = 0; it < NT; ++it) {
        const int jb = it * JC;
        const float sub0 = 0.5f * sq[jb + lane];        // hidden under GEMM
        const float sub1 = 0.5f * sq[jb + 64 + lane];

        float acc0[8], acc1[8];
        #pragma unroll
        for (int r = 0; r < 8; ++r) { acc0[r] = 0.f; acc1[r] = 0.f; }

        #pragma unroll 2
        for (int pg = 0; pg < D / 4; ++pg) {            // 4 d's per iter
            float4 a[8];
            #pragma unroll
            for (int r = 0; r < 8; ++r)                 // uniform addr -> s_load
                a[r] = *reinterpret_cast<const float4*>(xr + (size_t)r * D + 4 * pg);
            const float2 b00 = xjP[(2 * pg + 0) * JC + lane];
            const float2 b01 = xjP[(2 * pg + 0) * JC + 64 + lane];
            const float2 b10 = xjP[(2 * pg + 1) * JC + lane];
            const float2 b11 = xjP[(2 * pg + 1) * JC + 64 + lane];
            #pragma unroll
            for (int r = 0; r < 8; ++r) {               // d-ascending (numerics)
                acc0[r] = fmaf(a[r].x, b00.x, acc0[r]);
                acc0[r] = fmaf(a[r].y, b00.y, acc0[r]);
                acc0[r] = fmaf(a[r].z, b10.x, acc0[r]);
                acc0[r] = fmaf(a[r].w, b10.y, acc0[r]);
                acc1[r] = fmaf(a[r].x, b01.x, acc1[r]);
                acc1[r] = fmaf(a[r].y, b01.y, acc1[r]);
                acc1[r] = fmaf(a[r].z, b11.x, acc1[r]);
                acc1[r] = fmaf(a[r].w, b11.y, acc1[r]);
            }
        }
        __syncthreads();                   // all waves done reading xjP
        if (it + 1 < NT) {
            #pragma unroll
            for (int s = 0; s < NSTG; ++s) {
                const int e = s * 512 + t;
                const int j = e & (JC - 1), dg = e >> 7;
                xjP[(2 * dg + 0) * JC + j] = make_float2(stg[s].x, stg[s].y);
                xjP[(2 * dg + 1) * JC + j] = make_float2(stg[s].z, stg[s].w);
            }
        }
        __syncthreads();                   // next tile staged
        if (it + 2 < NT) {
            const int jb2 = (it + 2) * JC;
            #pragma unroll
            for (int s = 0; s < NSTG; ++s) {
                const int e = s * 512 + t;
                const int j = e & (JC - 1), dg = e >> 7;
                stg[s] = *reinterpret_cast<const float4*>(
                    X + (size_t)(jb2 + j) * D + 4 * dg);
            }
        }

        // scan (pure VALU/shuffle; hides the global prefetch latency)
        #pragma unroll
        for (int r = 0; r < 8; ++r) {
            if (it == 0) {                     // seed from cols 0..31
                const float s0 = acc0[r] - sub0;
                tv[r] = s0;
                tidx[r] = lane;
                float m = (lane < KNN) ? s0 : INF;
                #pragma unroll
                for (int off = 32; off; off >>= 1) m = fminf(m, __shfl_down(m, off));
                minv[r] = __shfl(m, 0);
            }
            #pragma unroll
            for (int h = 0; h < 2; ++h) {
                const float sv = (h ? acc1[r] : acc0[r]) - (h ? sub1 : sub0);
                unsigned long long mask = __ballot(sv > minv[r]);
                if (it == 0 && h == 0) mask &= 0xFFFFFFFF00000000ULL;  // seeded
                while (mask) {
                    const int l = __builtin_ctzll(mask);  // ascending j => stable
                    mask &= mask - 1;
                    const float cv = __shfl(sv, l);
                    if (!(cv > minv[r])) continue;
                    const int cj = it * JC + h * 64 + l;
                    float v  = (lane < KNN) ? tv[r] : INF;
                    int   si = (lane < KNN) ? tidx[r] : 0x7fffffff;
                    int   pos = lane;
                    float v2 = INF;
                    #pragma unroll
                    for (int off = 32; off; off >>= 1) {
                        const float ov  = __shfl_down(v, off);
                        const int   oi  = __shfl_down(si, off);
                        const int   op  = __shfl_down(pos, off);
                        const float ov2 = __shfl_down(v2, off);
                        const float rest = fminf(v2, ov2);
                        const bool take = (ov < v) || (ov == v && oi > si);
                        v2 = fminf(rest, take ? v : ov);
                        if (take) { v = ov; si = oi; pos = op; }
                    }
                    const float minval = __shfl(v, 0);
                    const int   minpos = __shfl(pos, 0);
                    const float min2   = __shfl(v2, 0);
                    if (cv > minval) {
                        if (lane == minpos) { tv[r] = cv; tidx[r] = cj; }
                        minv[r] = fminf(min2, cv);  // uniform
                    }
                }
            }
        }
    }

    if (lane < KNN) {
        #pragma unroll
        for (int r = 0; r < 8; ++r)
            topIdx[(size_t)(rowBase + waveU * 8 + r) * KNN + lane] = tidx[r];
    }
}

// ---------------- gather + MLP + pool + out ----------------
// h_k = A@nbr_k + B@x; pooled = mean_k clip(h_k); out = [pooled, x] @ W2^T.
// Wave -> (row, k-group); neighbor rows via uniform s_load (no LDS gather).
// Lane -> hh pair {2l, 2l+1}: A/B weights as float2 LDS reads (2-way = free).
template<int D, int LAYER>
__global__ __launch_bounds__(512)
void mlp_kernel(const float* __restrict__ X, const int* __restrict__ topIdx,
                const float* __restrict__ W, const float* __restrict__ W2,
                float* __restrict__ out) {
    constexpr int RPB = 2, WPR = 4, KPT = 8;   // 8 waves = RPB rows x WPR k-groups
    constexpr int W2C  = HDIM + D;
    constexpr int SPL2 = 512 / (RPB * ODIM);   // 4
    constexpr int CL   = W2C / SPL2;
    __shared__ float AT[D * HDIM];             // [d][hh]: B^T first, then A^T
    __shared__ float xi[RPB][D];
    __shared__ float part[RPB][WPR][HDIM];

    const int t = threadIdx.x;
    const int lane = t & 63;
    const int waveU = __builtin_amdgcn_readfirstlane(t >> 6);
    const int rowBase = blockIdx.x * RPB;
    const int row = waveU / WPR;
    const int wkb = waveU % WPR;
    const int hh2 = 2 * lane;                  // lane's hh pair

    // phase 0: stage xi and B^T
    if (t < RPB * D / 4) {
        const int i = t / (D / 4), dg = t % (D / 4);
        const float4 v = *reinterpret_cast<const float4*>(
            X + (size_t)(rowBase + i) * D + 4 * dg);
        xi[i][4 * dg + 0] = v.x; xi[i][4 * dg + 1] = v.y;
        xi[i][4 * dg + 2] = v.z; xi[i][4 * dg + 3] = v.w;
    }
    for (int e = t; e < HDIM * D / 4; e += 512) {
        const int hh = e % HDIM, dg = e / HDIM;
        const float4 v = *reinterpret_cast<const float4*>(
            W + (size_t)hh * (2 * D) + D + 4 * dg);          // B = W[:, D:2D]
        AT[(4 * dg + 0) * HDIM + hh] = v.x; AT[(4 * dg + 1) * HDIM + hh] = v.y;
        AT[(4 * dg + 2) * HDIM + hh] = v.z; AT[(4 * dg + 3) * HDIM + hh] = v.w;
    }
    __syncthreads();

    // phase 1: hself (lane's 2 hh) in registers
    float hs0 = 0.f, hs1 = 0.f;
    #pragma unroll 8
    for (int d = 0; d < D; ++d) {
        const float a = xi[row][d];            // broadcast LDS read
        const float2 b = *reinterpret_cast<const float2*>(&AT[d * HDIM + hh2]);
        hs0 = fmaf(b.x, a, hs0);
        hs1 = fmaf(b.y, a, hs1);
    }
    __syncthreads();                           // done reading AT-as-B^T

    // phase 1b: restage A^T
    for (int e = t; e < HDIM * D / 4; e += 512) {
        const int hh = e % HDIM, dg = e / HDIM;
        const float4 v = *reinterpret_cast<const float4*>(
            W + (size_t)hh * (2 * D) + 4 * dg);              // A = W[:, 0:D]
        AT[(4 * dg + 0) * HDIM + hh] = v.x; AT[(4 * dg + 1) * HDIM + hh] = v.y;
        AT[(4 * dg + 2) * HDIM + hh] = v.z; AT[(4 * dg + 3) * HDIM + hh] = v.w;
    }
    __syncthreads();

    // phase 2: GEMM; B-operand (neighbor rows) via uniform s_load
    const int* __restrict__ tIdx = topIdx + (size_t)(rowBase + row) * KNN + wkb * KPT;
    const float* nrow[KPT];
    #pragma unroll
    for (int r = 0; r < KPT; ++r)
        nrow[r] = X + (size_t)tIdx[r] * D;

    float acc0[KPT], acc1[KPT];
    #pragma unroll
    for (int r = 0; r < KPT; ++r) { acc0[r] = 0.f; acc1[r] = 0.f; }

    for (int dg = 0; dg < D / 4; ++dg) {
        float4 b[KPT];
        #pragma unroll
        for (int r = 0; r < KPT; ++r)          // uniform -> s_load_dwordx4
            b[r] = *reinterpret_cast<const float4*>(nrow[r] + 4 * dg);
        const float2 a0 = *reinterpret_cast<const float2*>(&AT[(4 * dg + 0) * HDIM + hh2]);
        const float2 a1 = *reinterpret_cast<const float2*>(&AT[(4 * dg + 1) * HDIM + hh2]);
        const float2 a2 = *reinterpret_cast<const float2*>(&AT[(4 * dg + 2) * HDIM + hh2]);
        const float2 a3 = *reinterpret_cast<const float2*>(&AT[(4 * dg + 3) * HDIM + hh2]);
        #pragma unroll
        for (int r = 0; r < KPT; ++r) {        // d-ascending accumulation
            acc0[r] = fmaf(a0.x, b[r].x, acc0[r]); acc1[r] = fmaf(a0.y, b[r].x, acc1[r]);
            acc0[r] = fmaf(a1.x, b[r].y, acc0[r]); acc1[r] = fmaf(a1.y, b[r].y, acc1[r]);
            acc0[r] = fmaf(a2.x, b[r].z, acc0[r]); acc1[r] = fmaf(a2.y, b[r].z, acc1[r]);
            acc0[r] = fmaf(a3.x, b[r].w, acc0[r]); acc1[r] = fmaf(a3.y, b[r].w, acc1[r]);
        }
    }

    // pooling partials (clip then sum over this wave's KPT neighbors)
    float p0 = 0.f, p1 = 0.f;
    #pragma unroll
    for (int r = 0; r < KPT; ++r) {
        p0 += fminf(1.f, fmaxf(-1.f, acc0[r] + hs0));
        p1 += fminf(1.f, fmaxf(-1.f, acc1[r] + hs1));
    }
    *reinterpret_cast<float2*>(&part[row][wkb][hh2]) =
        make_float2(p0 * (1.f / KNN), p1 * (1.f / KNN));
    __syncthreads();

    // phase 3: out = [pooled, x] @ W2^T, split over SPL2 column chunks
    {
        const int og   = t / SPL2;
        const int spl  = t % SPL2;
        const int orow = og >> 6, o = og & 63;
        const int c0   = spl * CL;
        float s = 0.f;
        for (int c = c0; c < c0 + CL; ++c) {
            float vsrc;
            if (c < HDIM) {
                vsrc = part[orow][0][c] + part[orow][1][c]
                     + part[orow][2][c] + part[orow][3][c];
            } else {
                vsrc = xi[orow][c - HDIM];
            }
            s = fmaf(vsrc, W2[(size_t)o * W2C + c], s);
        }
        #pragma unroll
        for (int off = SPL2 / 2; off; off >>= 1) s += __shfl_down(s, off);
        if (spl == 0) {
            if (LAYER == 0)
                out[(size_t)(rowBase + orow) * 128 + 64 + o] = s;  // x1 cols 64..127
            else
                out[(size_t)(rowBase + orow) * ODIM + o] = s;      // final output
        }
    }
    if (LAYER == 0 && t < RPB * 64) {
        const int orow = t >> 6, d = t & 63;
        out[(size_t)(rowBase + orow) * 128 + d] = xi[orow][d];     // x1 cols 0..63
    }
}

extern "C" void kernel_launch(void* const* d_in, const int* in_sizes, int n_in,
                              void* d_out, int out_size, void* d_ws, size_t ws_size,
                              hipStream_t stream) {
    const float* x    = (const float*)d_in[0];
    const float* w0   = (const float*)d_in[1];
    const float* w2_0 = (const float*)d_in[2];
    const float* w1   = (const float*)d_in[3];
    const float* w2_1 = (const float*)d_in[4];
    float* out = (float*)d_out;

    char* ws = (char*)d_ws;
    float* sq  = (float*)ws;                                     // NP floats
    int*   idx = (int*)(ws + (size_t)NP * 4);                    // NP*32 ints
    float* x1  = (float*)(ws + (size_t)NP * 4 + (size_t)NP * KNN * 4);  // NP*128

    // layer 0 (D = 64)
    sq_kernel<64><<<NP / 4, 256, 0, stream>>>(x, sq);
    topk_kernel<64><<<NP / 64, 512, 0, stream>>>(x, sq, idx);
    mlp_kernel<64, 0><<<NP / 2, 512, 0, stream>>>(x, idx, w0, w2_0, x1);

    // layer 1 (D = 128, x1 = [x, o0])
    sq_kernel<128><<<NP / 4, 256, 0, stream>>>(x1, sq);
    topk_kernel<128><<<NP / 64, 512, 0, stream>>>(x1, sq, idx);
    mlp_kernel<128, 1><<<NP / 2, 512, 0, stream>>>(x1, idx, w1, w2_1, out);
}

// Round 7
// 4070.184 us; speedup vs baseline: 3.1463x; 1.4492x over previous
//
#include <hip/hip_runtime.h>

#define NP   16384
#define KNN  32
#define HDIM 128
#define ODIM 64

// ---------------- squared norms ----------------
template<int D>
__global__ __launch_bounds__(256)
void sq_kernel(const float* __restrict__ X, float* __restrict__ sq) {
    const int lane = threadIdx.x & 63;
    const int row  = blockIdx.x * 4 + (threadIdx.x >> 6);
    float s = 0.f;
    #pragma unroll
    for (int d = lane; d < D; d += 64) {
        const float v = X[(size_t)row * D + d];
        s = fmaf(v, v, s);
    }
    #pragma unroll
    for (int off = 32; off; off >>= 1) s += __shfl_down(s, off);
    if (lane == 0) sq[row] = s;
}

// ---------------- top-32 neighbors (streaming, sorted register top-k) -------
// score_j = dot(x_i,x_j) - 0.5*sq_j (argmax score == argmin d2 per row).
// 8 waves; wave owns 8 rows; lane owns cols {lane, lane+64} of a 128-col tile.
// Top-32 kept SORTED (value desc, index asc on ties) across lanes 0..31:
// insert = 1 ballot + 2 shfl_up + 1 shfl  (vs 6-step argmin reduce).
template<int D>
__global__ __launch_bounds__(512)
void topk_kernel(const float* __restrict__ X, const float* __restrict__ sq,
                 int* __restrict__ topIdx) {
    constexpr int TI = 64, JC = 128;
    constexpr int NT = NP / JC;
    constexpr int NSTG = JC * D / 4 / 512;   // float4/thread per j-tile
    __shared__ float2 xjP[(D / 2) * JC];     // [pair p][j]: (d=2p, d=2p+1) of col j

    const int t = threadIdx.x;
    const int lane = t & 63;
    const int waveU = __builtin_amdgcn_readfirstlane(t >> 6);   // SGPR wave id
    const int rowBase = blockIdx.x * TI;
    const float* __restrict__ xr = X + (size_t)(rowBase + waveU * 8) * D;
    const float INF = __builtin_inff();

    // sorted top-32 per row: lane l<32 holds rank-l entry (desc value)
    float tv[8]; int tidx[8]; float minv[8];
    #pragma unroll
    for (int r = 0; r < 8; ++r) { tv[r] = -INF; tidx[r] = 0x7fffffff; minv[r] = -INF; }

    float4 stg[NSTG];
    // stage tile 0
    #pragma unroll
    for (int s = 0; s < NSTG; ++s) {
        const int e = s * 512 + t;
        const int j = e & (JC - 1), dg = e >> 7;
        stg[s] = *reinterpret_cast<const float4*>(X + (size_t)j * D + 4 * dg);
    }
    #pragma unroll
    for (int s = 0; s < NSTG; ++s) {
        const int e = s * 512 + t;
        const int j = e & (JC - 1), dg = e >> 7;
        xjP[(2 * dg + 0) * JC + j] = make_float2(stg[s].x, stg[s].y);
        xjP[(2 * dg + 1) * JC + j] = make_float2(stg[s].z, stg[s].w);
    }
    __syncthreads();
    // prefetch tile 1
    #pragma unroll
    for (int s = 0; s < NSTG; ++s) {
        const int e = s * 512 + t;
        const int j = e & (JC - 1), dg = e >> 7;
        stg[s] = *reinterpret_cast<const float4*>(X + (size_t)(JC + j) * D + 4 * dg);
    }

    for (int it = 0; it < NT; ++it) {
        const int jb = it * JC;
        const float sub0 = 0.5f * sq[jb + lane];        // hidden under GEMM
        const float sub1 = 0.5f * sq[jb + 64 + lane];

        float acc0[8], acc1[8];
        #pragma unroll
        for (int r = 0; r < 8; ++r) { acc0[r] = 0.f; acc1[r] = 0.f; }

        #pragma unroll 2
        for (int pg = 0; pg < D / 4; ++pg) {            // 4 d's per iter
            float4 a[8];
            #pragma unroll
            for (int r = 0; r < 8; ++r)                 // uniform addr -> s_load
                a[r] = *reinterpret_cast<const float4*>(xr + (size_t)r * D + 4 * pg);
            const float2 b00 = xjP[(2 * pg + 0) * JC + lane];
            const float2 b01 = xjP[(2 * pg + 0) * JC + 64 + lane];
            const float2 b10 = xjP[(2 * pg + 1) * JC + lane];
            const float2 b11 = xjP[(2 * pg + 1) * JC + 64 + lane];
            #pragma unroll
            for (int r = 0; r < 8; ++r) {               // d-ascending (numerics)
                acc0[r] = fmaf(a[r].x, b00.x, acc0[r]);
                acc0[r] = fmaf(a[r].y, b00.y, acc0[r]);
                acc0[r] = fmaf(a[r].z, b10.x, acc0[r]);
                acc0[r] = fmaf(a[r].w, b10.y, acc0[r]);
                acc1[r] = fmaf(a[r].x, b01.x, acc1[r]);
                acc1[r] = fmaf(a[r].y, b01.y, acc1[r]);
                acc1[r] = fmaf(a[r].z, b11.x, acc1[r]);
                acc1[r] = fmaf(a[r].w, b11.y, acc1[r]);
            }
        }
        __syncthreads();                   // all waves done reading xjP
        if (it + 1 < NT) {
            #pragma unroll
            for (int s = 0; s < NSTG; ++s) {
                const int e = s * 512 + t;
                const int j = e & (JC - 1), dg = e >> 7;
                xjP[(2 * dg + 0) * JC + j] = make_float2(stg[s].x, stg[s].y);
                xjP[(2 * dg + 1) * JC + j] = make_float2(stg[s].z, stg[s].w);
            }
        }
        __syncthreads();                   // next tile staged
        if (it + 2 < NT) {
            const int jb2 = (it + 2) * JC;
            #pragma unroll
            for (int s = 0; s < NSTG; ++s) {
                const int e = s * 512 + t;
                const int j = e & (JC - 1), dg = e >> 7;
                stg[s] = *reinterpret_cast<const float4*>(
                    X + (size_t)(jb2 + j) * D + 4 * dg);
            }
        }

        // scan: sorted-insert top-k (pure ballot/shuffle, hides prefetch latency)
        #pragma unroll
        for (int r = 0; r < 8; ++r) {
            #pragma unroll
            for (int h = 0; h < 2; ++h) {
                const float sv = (h ? acc1[r] : acc0[r]) - (h ? sub1 : sub0);
                unsigned long long mask = __ballot(sv > minv[r]);
                while (mask) {
                    const int l = __builtin_ctzll(mask);  // ascending j => stable
                    mask &= mask - 1;
                    const float cv = __shfl(sv, l);
                    if (!(cv > minv[r])) continue;        // minv rose since ballot
                    const int cj = jb + h * 64 + l;
                    // insertion position: after all entries >= cv (index-asc ties)
                    const bool ge = (lane < KNN) && (tv[r] >= cv);
                    const int p = __popcll(__ballot(ge)); // 0..31 (cv > minv)
                    const float upv = __shfl_up(tv[r], 1);
                    const int   upi = __shfl_up(tidx[r], 1);
                    if (lane == p)                        { tv[r] = cv;  tidx[r] = cj; }
                    else if (lane > p && lane < KNN)      { tv[r] = upv; tidx[r] = upi; }
                    minv[r] = __shfl(tv[r], KNN - 1);     // lane 31 = new min
                }
            }
        }
    }

    if (lane < KNN) {
        #pragma unroll
        for (int r = 0; r < 8; ++r)
            topIdx[(size_t)(rowBase + waveU * 8 + r) * KNN + lane] = tidx[r];
    }
}

// ---------------- gather + MLP + pool + out ----------------
// h_k = A@nbr_k + B@x; pooled = mean_k clip(h_k); out = [pooled, x] @ W2^T.
// Wave -> (row, k-group); neighbor rows via uniform s_load (no LDS gather).
// Lane -> hh pair {2l, 2l+1}: A/B weights as float2 LDS reads (2-way = free).
template<int D, int LAYER>
__global__ __launch_bounds__(512)
void mlp_kernel(const float* __restrict__ X, const int* __restrict__ topIdx,
                const float* __restrict__ W, const float* __restrict__ W2,
                float* __restrict__ out) {
    constexpr int RPB = 2, WPR = 4, KPT = 8;   // 8 waves = RPB rows x WPR k-groups
    constexpr int W2C  = HDIM + D;
    constexpr int SPL2 = 512 / (RPB * ODIM);   // 4
    constexpr int CL   = W2C / SPL2;
    __shared__ float AT[D * HDIM];             // [d][hh]: B^T first, then A^T
    __shared__ float xi[RPB][D];
    __shared__ float part[RPB][WPR][HDIM];

    const int t = threadIdx.x;
    const int lane = t & 63;
    const int waveU = __builtin_amdgcn_readfirstlane(t >> 6);
    const int rowBase = blockIdx.x * RPB;
    const int row = waveU / WPR;
    const int wkb = waveU % WPR;
    const int hh2 = 2 * lane;                  // lane's hh pair

    // phase 0: stage xi and B^T
    if (t < RPB * D / 4) {
        const int i = t / (D / 4), dg = t % (D / 4);
        const float4 v = *reinterpret_cast<const float4*>(
            X + (size_t)(rowBase + i) * D + 4 * dg);
        xi[i][4 * dg + 0] = v.x; xi[i][4 * dg + 1] = v.y;
        xi[i][4 * dg + 2] = v.z; xi[i][4 * dg + 3] = v.w;
    }
    for (int e = t; e < HDIM * D / 4; e += 512) {
        const int hh = e % HDIM, dg = e / HDIM;
        const float4 v = *reinterpret_cast<const float4*>(
            W + (size_t)hh * (2 * D) + D + 4 * dg);          // B = W[:, D:2D]
        AT[(4 * dg + 0) * HDIM + hh] = v.x; AT[(4 * dg + 1) * HDIM + hh] = v.y;
        AT[(4 * dg + 2) * HDIM + hh] = v.z; AT[(4 * dg + 3) * HDIM + hh] = v.w;
    }
    __syncthreads();

    // phase 1: hself (lane's 2 hh) in registers
    float hs0 = 0.f, hs1 = 0.f;
    #pragma unroll 8
    for (int d = 0; d < D; ++d) {
        const float a = xi[row][d];            // broadcast LDS read
        const float2 b = *reinterpret_cast<const float2*>(&AT[d * HDIM + hh2]);
        hs0 = fmaf(b.x, a, hs0);
        hs1 = fmaf(b.y, a, hs1);
    }
    __syncthreads();                           // done reading AT-as-B^T

    // phase 1b: restage A^T
    for (int e = t; e < HDIM * D / 4; e += 512) {
        const int hh = e % HDIM, dg = e / HDIM;
        const float4 v = *reinterpret_cast<const float4*>(
            W + (size_t)hh * (2 * D) + 4 * dg);              // A = W[:, 0:D]
        AT[(4 * dg + 0) * HDIM + hh] = v.x; AT[(4 * dg + 1) * HDIM + hh] = v.y;
        AT[(4 * dg + 2) * HDIM + hh] = v.z; AT[(4 * dg + 3) * HDIM + hh] = v.w;
    }
    __syncthreads();

    // phase 2: GEMM; B-operand (neighbor rows) via uniform s_load
    const int* __restrict__ tIdx = topIdx + (size_t)(rowBase + row) * KNN + wkb * KPT;
    const float* nrow[KPT];
    #pragma unroll
    for (int r = 0; r < KPT; ++r)
        nrow[r] = X + (size_t)tIdx[r] * D;

    float acc0[KPT], acc1[KPT];
    #pragma unroll
    for (int r = 0; r < KPT; ++r) { acc0[r] = 0.f; acc1[r] = 0.f; }

    for (int dg = 0; dg < D / 4; ++dg) {
        float4 b[KPT];
        #pragma unroll
        for (int r = 0; r < KPT; ++r)          // uniform -> s_load_dwordx4
            b[r] = *reinterpret_cast<const float4*>(nrow[r] + 4 * dg);
        const float2 a0 = *reinterpret_cast<const float2*>(&AT[(4 * dg + 0) * HDIM + hh2]);
        const float2 a1 = *reinterpret_cast<const float2*>(&AT[(4 * dg + 1) * HDIM + hh2]);
        const float2 a2 = *reinterpret_cast<const float2*>(&AT[(4 * dg + 2) * HDIM + hh2]);
        const float2 a3 = *reinterpret_cast<const float2*>(&AT[(4 * dg + 3) * HDIM + hh2]);
        #pragma unroll
        for (int r = 0; r < KPT; ++r) {        // d-ascending accumulation
            acc0[r] = fmaf(a0.x, b[r].x, acc0[r]); acc1[r] = fmaf(a0.y, b[r].x, acc1[r]);
            acc0[r] = fmaf(a1.x, b[r].y, acc0[r]); acc1[r] = fmaf(a1.y, b[r].y, acc1[r]);
            acc0[r] = fmaf(a2.x, b[r].z, acc0[r]); acc1[r] = fmaf(a2.y, b[r].z, acc1[r]);
            acc0[r] = fmaf(a3.x, b[r].w, acc0[r]); acc1[r] = fmaf(a3.y, b[r].w, acc1[r]);
        }
    }

    // pooling partials (clip then sum over this wave's KPT neighbors)
    float p0 = 0.f, p1 = 0.f;
    #pragma unroll
    for (int r = 0; r < KPT; ++r) {
        p0 += fminf(1.f, fmaxf(-1.f, acc0[r] + hs0));
        p1 += fminf(1.f, fmaxf(-1.f, acc1[r] + hs1));
    }
    *reinterpret_cast<float2*>(&part[row][wkb][hh2]) =
        make_float2(p0 * (1.f / KNN), p1 * (1.f / KNN));
    __syncthreads();

    // phase 3: out = [pooled, x] @ W2^T, split over SPL2 column chunks
    {
        const int og   = t / SPL2;
        const int spl  = t % SPL2;
        const int orow = og >> 6, o = og & 63;
        const int c0   = spl * CL;
        float s = 0.f;
        for (int c = c0; c < c0 + CL; ++c) {
            float vsrc;
            if (c < HDIM) {
                vsrc = part[orow][0][c] + part[orow][1][c]
                     + part[orow][2][c] + part[orow][3][c];
            } else {
                vsrc = xi[orow][c - HDIM];
            }
            s = fmaf(vsrc, W2[(size_t)o * W2C + c], s);
        }
        #pragma unroll
        for (int off = SPL2 / 2; off; off >>= 1) s += __shfl_down(s, off);
        if (spl == 0) {
            if (LAYER == 0)
                out[(size_t)(rowBase + orow) * 128 + 64 + o] = s;  // x1 cols 64..127
            else
                out[(size_t)(rowBase + orow) * ODIM + o] = s;      // final output
        }
    }
    if (LAYER == 0 && t < RPB * 64) {
        const int orow = t >> 6, d = t & 63;
        out[(size_t)(rowBase + orow) * 128 + d] = xi[orow][d];     // x1 cols 0..63
    }
}

extern "C" void kernel_launch(void* const* d_in, const int* in_sizes, int n_in,
                              void* d_out, int out_size, void* d_ws, size_t ws_size,
                              hipStream_t stream) {
    const float* x    = (const float*)d_in[0];
    const float* w0   = (const float*)d_in[1];
    const float* w2_0 = (const float*)d_in[2];
    const float* w1   = (const float*)d_in[3];
    const float* w2_1 = (const float*)d_in[4];
    float* out = (float*)d_out;

    char* ws = (char*)d_ws;
    float* sq  = (float*)ws;                                     // NP floats
    int*   idx = (int*)(ws + (size_t)NP * 4);                    // NP*32 ints
    float* x1  = (float*)(ws + (size_t)NP * 4 + (size_t)NP * KNN * 4);  // NP*128

    // layer 0 (D = 64)
    sq_kernel<64><<<NP / 4, 256, 0, stream>>>(x, sq);
    topk_kernel<64><<<NP / 64, 512, 0, stream>>>(x, sq, idx);
    mlp_kernel<64, 0><<<NP / 2, 512, 0, stream>>>(x, idx, w0, w2_0, x1);

    // layer 1 (D = 128, x1 = [x, o0])
    sq_kernel<128><<<NP / 4, 256, 0, stream>>>(x1, sq);
    topk_kernel<128><<<NP / 64, 512, 0, stream>>>(x1, sq, idx);
    mlp_kernel<128, 1><<<NP / 2, 512, 0, stream>>>(x1, idx, w1, w2_1, out);
}

// Round 8
// 3415.593 us; speedup vs baseline: 3.7493x; 1.1916x over previous
//
#include <hip/hip_runtime.h>

#define NP   16384
#define KNN  32
#define HDIM 128
#define ODIM 64

// ---------------- squared norms ----------------
template<int D>
__global__ __launch_bounds__(256)
void sq_kernel(const float* __restrict__ X, float* __restrict__ sq) {
    const int lane = threadIdx.x & 63;
    const int row  = blockIdx.x * 4 + (threadIdx.x >> 6);
    float s = 0.f;
    #pragma unroll
    for (int d = lane; d < D; d += 64) {
        const float v = X[(size_t)row * D + d];
        s = fmaf(v, v, s);
    }
    #pragma unroll
    for (int off = 32; off; off >>= 1) s += __shfl_down(s, off);
    if (lane == 0) sq[row] = s;
}

// ---------------- top-32 neighbors (streaming, sorted register top-k) -------
// score_j = dot(x_i,x_j) - 0.5*sq_j (argmax score == argmin d2 per row).
// 8 waves; wave owns R=4 rows (TI=32 -> 512 blocks = 2 blocks/CU for chain
// overlap); lane owns cols {lane, lane+64} of a 128-col tile.
// Top-32 kept SORTED (value desc, index asc on ties) across lanes 0..31:
// insert = 1 ballot + 2 shfl_up + 1 shfl.
template<int D>
__global__ __launch_bounds__(512)
void topk_kernel(const float* __restrict__ X, const float* __restrict__ sq,
                 int* __restrict__ topIdx) {
    constexpr int TI = 32, JC = 128;
    constexpr int R  = TI / 8;               // rows per wave
    constexpr int NT = NP / JC;
    constexpr int NSTG = JC * D / 4 / 512;   // float4/thread per j-tile
    __shared__ float2 xjP[(D / 2) * JC];     // [pair p][j]: (d=2p, d=2p+1) of col j

    const int t = threadIdx.x;
    const int lane = t & 63;
    const int waveU = __builtin_amdgcn_readfirstlane(t >> 6);   // SGPR wave id
    const int rowBase = blockIdx.x * TI;
    const float* __restrict__ xr = X + (size_t)(rowBase + waveU * R) * D;
    const float INF = __builtin_inff();

    // sorted top-32 per row: lane l<32 holds rank-l entry (desc value)
    float tv[R]; int tidx[R]; float minv[R];
    #pragma unroll
    for (int r = 0; r < R; ++r) { tv[r] = -INF; tidx[r] = 0x7fffffff; minv[r] = -INF; }

    float4 stg[NSTG];
    // stage tile 0
    #pragma unroll
    for (int s = 0; s < NSTG; ++s) {
        const int e = s * 512 + t;
        const int j = e & (JC - 1), dg = e >> 7;
        stg[s] = *reinterpret_cast<const float4*>(X + (size_t)j * D + 4 * dg);
    }
    #pragma unroll
    for (int s = 0; s < NSTG; ++s) {
        const int e = s * 512 + t;
        const int j = e & (JC - 1), dg = e >> 7;
        xjP[(2 * dg + 0) * JC + j] = make_float2(stg[s].x, stg[s].y);
        xjP[(2 * dg + 1) * JC + j] = make_float2(stg[s].z, stg[s].w);
    }
    __syncthreads();
    // prefetch tile 1
    #pragma unroll
    for (int s = 0; s < NSTG; ++s) {
        const int e = s * 512 + t;
        const int j = e & (JC - 1), dg = e >> 7;
        stg[s] = *reinterpret_cast<const float4*>(X + (size_t)(JC + j) * D + 4 * dg);
    }

    for (int it = 0; it < NT; ++it) {
        const int jb = it * JC;
        const float sub0 = 0.5f * sq[jb + lane];        // hidden under GEMM
        const float sub1 = 0.5f * sq[jb + 64 + lane];

        float acc0[R], acc1[R];
        #pragma unroll
        for (int r = 0; r < R; ++r) { acc0[r] = 0.f; acc1[r] = 0.f; }

        #pragma unroll 2
        for (int pg = 0; pg < D / 4; ++pg) {            // 4 d's per iter
            float4 a[R];
            #pragma unroll
            for (int r = 0; r < R; ++r)                 // uniform addr -> s_load
                a[r] = *reinterpret_cast<const float4*>(xr + (size_t)r * D + 4 * pg);
            const float2 b00 = xjP[(2 * pg + 0) * JC + lane];
            const float2 b01 = xjP[(2 * pg + 0) * JC + 64 + lane];
            const float2 b10 = xjP[(2 * pg + 1) * JC + lane];
            const float2 b11 = xjP[(2 * pg + 1) * JC + 64 + lane];
            #pragma unroll
            for (int r = 0; r < R; ++r) {               // d-ascending (numerics)
                acc0[r] = fmaf(a[r].x, b00.x, acc0[r]);
                acc0[r] = fmaf(a[r].y, b00.y, acc0[r]);
                acc0[r] = fmaf(a[r].z, b10.x, acc0[r]);
                acc0[r] = fmaf(a[r].w, b10.y, acc0[r]);
                acc1[r] = fmaf(a[r].x, b01.x, acc1[r]);
                acc1[r] = fmaf(a[r].y, b01.y, acc1[r]);
                acc1[r] = fmaf(a[r].z, b11.x, acc1[r]);
                acc1[r] = fmaf(a[r].w, b11.y, acc1[r]);
            }
        }
        __syncthreads();                   // all waves done reading xjP
        if (it + 1 < NT) {
            #pragma unroll
            for (int s = 0; s < NSTG; ++s) {
                const int e = s * 512 + t;
                const int j = e & (JC - 1), dg = e >> 7;
                xjP[(2 * dg + 0) * JC + j] = make_float2(stg[s].x, stg[s].y);
                xjP[(2 * dg + 1) * JC + j] = make_float2(stg[s].z, stg[s].w);
            }
        }
        __syncthreads();                   // next tile staged
        if (it + 2 < NT) {
            const int jb2 = (it + 2) * JC;
            #pragma unroll
            for (int s = 0; s < NSTG; ++s) {
                const int e = s * 512 + t;
                const int j = e & (JC - 1), dg = e >> 7;
                stg[s] = *reinterpret_cast<const float4*>(
                    X + (size_t)(jb2 + j) * D + 4 * dg);
            }
        }

        // scan: sorted-insert top-k (pure ballot/shuffle, hides prefetch latency)
        #pragma unroll
        for (int r = 0; r < R; ++r) {
            #pragma unroll
            for (int h = 0; h < 2; ++h) {
                const float sv = (h ? acc1[r] : acc0[r]) - (h ? sub1 : sub0);
                unsigned long long mask = __ballot(sv > minv[r]);
                while (mask) {
                    const int l = __builtin_ctzll(mask);  // ascending j => stable
                    mask &= mask - 1;
                    const float cv = __shfl(sv, l);
                    if (!(cv > minv[r])) continue;        // minv rose since ballot
                    const int cj = jb + h * 64 + l;
                    // insertion position: after all entries >= cv (index-asc ties)
                    const bool ge = (lane < KNN) && (tv[r] >= cv);
                    const int p = __popcll(__ballot(ge)); // 0..31 (cv > minv)
                    const float upv = __shfl_up(tv[r], 1);
                    const int   upi = __shfl_up(tidx[r], 1);
                    if (lane == p)                        { tv[r] = cv;  tidx[r] = cj; }
                    else if (lane > p && lane < KNN)      { tv[r] = upv; tidx[r] = upi; }
                    minv[r] = __shfl(tv[r], KNN - 1);     // lane 31 = new min
                }
            }
        }
    }

    if (lane < KNN) {
        #pragma unroll
        for (int r = 0; r < R; ++r)
            topIdx[(size_t)(rowBase + waveU * R + r) * KNN + lane] = tidx[r];
    }
}

// ---------------- gather + MLP + pool + out ----------------
// h_k = A@nbr_k + B@x; pooled = mean_k clip(h_k); out = [pooled, x] @ W2^T.
// Wave -> (row, k-group); neighbor rows via uniform s_load (no LDS gather).
// Lane -> hh pair {2l, 2l+1}: A/B weights as float2 LDS reads (2-way = free).
template<int D, int LAYER>
__global__ __launch_bounds__(512)
void mlp_kernel(const float* __restrict__ X, const int* __restrict__ topIdx,
                const float* __restrict__ W, const float* __restrict__ W2,
                float* __restrict__ out) {
    constexpr int RPB = 2, WPR = 4, KPT = 8;   // 8 waves = RPB rows x WPR k-groups
    constexpr int W2C  = HDIM + D;
    constexpr int SPL2 = 512 / (RPB * ODIM);   // 4
    constexpr int CL   = W2C / SPL2;
    __shared__ float AT[D * HDIM];             // [d][hh]: B^T first, then A^T
    __shared__ float xi[RPB][D];
    __shared__ float part[RPB][WPR][HDIM];

    const int t = threadIdx.x;
    const int lane = t & 63;
    const int waveU = __builtin_amdgcn_readfirstlane(t >> 6);
    const int rowBase = blockIdx.x * RPB;
    const int row = waveU / WPR;
    const int wkb = waveU % WPR;
    const int hh2 = 2 * lane;                  // lane's hh pair

    // phase 0: stage xi and B^T
    if (t < RPB * D / 4) {
        const int i = t / (D / 4), dg = t % (D / 4);
        const float4 v = *reinterpret_cast<const float4*>(
            X + (size_t)(rowBase + i) * D + 4 * dg);
        xi[i][4 * dg + 0] = v.x; xi[i][4 * dg + 1] = v.y;
        xi[i][4 * dg + 2] = v.z; xi[i][4 * dg + 3] = v.w;
    }
    for (int e = t; e < HDIM * D / 4; e += 512) {
        const int hh = e % HDIM, dg = e / HDIM;
        const float4 v = *reinterpret_cast<const float4*>(
            W + (size_t)hh * (2 * D) + D + 4 * dg);          // B = W[:, D:2D]
        AT[(4 * dg + 0) * HDIM + hh] = v.x; AT[(4 * dg + 1) * HDIM + hh] = v.y;
        AT[(4 * dg + 2) * HDIM + hh] = v.z; AT[(4 * dg + 3) * HDIM + hh] = v.w;
    }
    __syncthreads();

    // phase 1: hself (lane's 2 hh) in registers
    float hs0 = 0.f, hs1 = 0.f;
    #pragma unroll 8
    for (int d = 0; d < D; ++d) {
        const float a = xi[row][d];            // broadcast LDS read
        const float2 b = *reinterpret_cast<const float2*>(&AT[d * HDIM + hh2]);
        hs0 = fmaf(b.x, a, hs0);
        hs1 = fmaf(b.y, a, hs1);
    }
    __syncthreads();                           // done reading AT-as-B^T

    // phase 1b: restage A^T
    for (int e = t; e < HDIM * D / 4; e += 512) {
        const int hh = e % HDIM, dg = e / HDIM;
        const float4 v = *reinterpret_cast<const float4*>(
            W + (size_t)hh * (2 * D) + 4 * dg);              // A = W[:, 0:D]
        AT[(4 * dg + 0) * HDIM + hh] = v.x; AT[(4 * dg + 1) * HDIM + hh] = v.y;
        AT[(4 * dg + 2) * HDIM + hh] = v.z; AT[(4 * dg + 3) * HDIM + hh] = v.w;
    }
    __syncthreads();

    // phase 2: GEMM; B-operand (neighbor rows) via uniform s_load
    const int* __restrict__ tIdx = topIdx + (size_t)(rowBase + row) * KNN + wkb * KPT;
    const float* nrow[KPT];
    #pragma unroll
    for (int r = 0; r < KPT; ++r)
        nrow[r] = X + (size_t)tIdx[r] * D;

    float acc0[KPT], acc1[KPT];
    #pragma unroll
    for (int r = 0; r < KPT; ++r) { acc0[r] = 0.f; acc1[r] = 0.f; }

    for (int dg = 0; dg < D / 4; ++dg) {
        float4 b[KPT];
        #pragma unroll
        for (int r = 0; r < KPT; ++r)          // uniform -> s_load_dwordx4
            b[r] = *reinterpret_cast<const float4*>(nrow[r] + 4 * dg);
        const float2 a0 = *reinterpret_cast<const float2*>(&AT[(4 * dg + 0) * HDIM + hh2]);
        const float2 a1 = *reinterpret_cast<const float2*>(&AT[(4 * dg + 1) * HDIM + hh2]);
        const float2 a2 = *reinterpret_cast<const float2*>(&AT[(4 * dg + 2) * HDIM + hh2]);
        const float2 a3 = *reinterpret_cast<const float2*>(&AT[(4 * dg + 3) * HDIM + hh2]);
        #pragma unroll
        for (int r = 0; r < KPT; ++r) {        // d-ascending accumulation
            acc0[r] = fmaf(a0.x, b[r].x, acc0[r]); acc1[r] = fmaf(a0.y, b[r].x, acc1[r]);
            acc0[r] = fmaf(a1.x, b[r].y, acc0[r]); acc1[r] = fmaf(a1.y, b[r].y, acc1[r]);
            acc0[r] = fmaf(a2.x, b[r].z, acc0[r]); acc1[r] = fmaf(a2.y, b[r].z, acc1[r]);
            acc0[r] = fmaf(a3.x, b[r].w, acc0[r]); acc1[r] = fmaf(a3.y, b[r].w, acc1[r]);
        }
    }

    // pooling partials (clip then sum over this wave's KPT neighbors)
    float p0 = 0.f, p1 = 0.f;
    #pragma unroll
    for (int r = 0; r < KPT; ++r) {
        p0 += fminf(1.f, fmaxf(-1.f, acc0[r] + hs0));
        p1 += fminf(1.f, fmaxf(-1.f, acc1[r] + hs1));
    }
    *reinterpret_cast<float2*>(&part[row][wkb][hh2]) =
        make_float2(p0 * (1.f / KNN), p1 * (1.f / KNN));
    __syncthreads();

    // phase 3: out = [pooled, x] @ W2^T, split over SPL2 column chunks
    {
        const int og   = t / SPL2;
        const int spl  = t % SPL2;
        const int orow = og >> 6, o = og & 63;
        const int c0   = spl * CL;
        float s = 0.f;
        for (int c = c0; c < c0 + CL; ++c) {
            float vsrc;
            if (c < HDIM) {
                vsrc = part[orow][0][c] + part[orow][1][c]
                     + part[orow][2][c] + part[orow][3][c];
            } else {
                vsrc = xi[orow][c - HDIM];
            }
            s = fmaf(vsrc, W2[(size_t)o * W2C + c], s);
        }
        #pragma unroll
        for (int off = SPL2 / 2; off; off >>= 1) s += __shfl_down(s, off);
        if (spl == 0) {
            if (LAYER == 0)
                out[(size_t)(rowBase + orow) * 128 + 64 + o] = s;  // x1 cols 64..127
            else
                out[(size_t)(rowBase + orow) * ODIM + o] = s;      // final output
        }
    }
    if (LAYER == 0 && t < RPB * 64) {
        const int orow = t >> 6, d = t & 63;
        out[(size_t)(rowBase + orow) * 128 + d] = xi[orow][d];     // x1 cols 0..63
    }
}

extern "C" void kernel_launch(void* const* d_in, const int* in_sizes, int n_in,
                              void* d_out, int out_size, void* d_ws, size_t ws_size,
                              hipStream_t stream) {
    const float* x    = (const float*)d_in[0];
    const float* w0   = (const float*)d_in[1];
    const float* w2_0 = (const float*)d_in[2];
    const float* w1   = (const float*)d_in[3];
    const float* w2_1 = (const float*)d_in[4];
    float* out = (float*)d_out;

    char* ws = (char*)d_ws;
    float* sq  = (float*)ws;                                     // NP floats
    int*   idx = (int*)(ws + (size_t)NP * 4);                    // NP*32 ints
    float* x1  = (float*)(ws + (size_t)NP * 4 + (size_t)NP * KNN * 4);  // NP*128

    // layer 0 (D = 64)
    sq_kernel<64><<<NP / 4, 256, 0, stream>>>(x, sq);
    topk_kernel<64><<<NP / 32, 512, 0, stream>>>(x, sq, idx);
    mlp_kernel<64, 0><<<NP / 2, 512, 0, stream>>>(x, idx, w0, w2_0, x1);

    // layer 1 (D = 128, x1 = [x, o0])
    sq_kernel<128><<<NP / 4, 256, 0, stream>>>(x1, sq);
    topk_kernel<128><<<NP / 32, 512, 0, stream>>>(x1, sq, idx);
    mlp_kernel<128, 1><<<NP / 2, 512, 0, stream>>>(x1, idx, w1, w2_1, out);
}